// Round 2
// baseline (317.262 us; speedup 1.0000x reference)
//
#include <hip/hip_runtime.h>

#define IMG_H 512
#define IMG_W 512
#define RH 16                       // output rows per wave-task
#define STRIPS (IMG_H / RH)         // 32
#define PLANE_N (IMG_H * IMG_W)
#define NSLOT 64
#define SLOT_STRIDE 8               // doubles (64 B apart) to spread atomic traffic

// f32-rounded Gaussian(sigma=1.5, k=3) weights, matching JAX's f32 computation
constexpr float W_E = 0.30780133f;
constexpr float W_C = 0.38439734f;
constexpr float C1v = 1e-4f;
constexpr float C2v = 9e-4f;

struct RowRegs { float a[8]; float b[8]; };

// Lane owns cols [col0, col0+8). Wave-uniform row => SGPR base + VGPR offset loads.
__device__ __forceinline__ void load_row(const float* __restrict__ A,
                                         const float* __restrict__ B,
                                         int row, int col0, RowRegs& s) {
    if ((unsigned)row < IMG_H) {            // wave-uniform branch
        const float* pa = A + (size_t)row * IMG_W + col0;
        const float* pb = B + (size_t)row * IMG_W + col0;
        const float4 a0 = ((const float4*)pa)[0];
        const float4 a1 = ((const float4*)pa)[1];
        const float4 b0 = ((const float4*)pb)[0];
        const float4 b1 = ((const float4*)pb)[1];
        s.a[0] = a0.x; s.a[1] = a0.y; s.a[2] = a0.z; s.a[3] = a0.w;
        s.a[4] = a1.x; s.a[5] = a1.y; s.a[6] = a1.z; s.a[7] = a1.w;
        s.b[0] = b0.x; s.b[1] = b0.y; s.b[2] = b0.z; s.b[3] = b0.w;
        s.b[4] = b1.x; s.b[5] = b1.y; s.b[6] = b1.z; s.b[7] = b1.w;
    } else {                                // rows -1 / 512+ are zero padding
#pragma unroll
        for (int c = 0; c < 8; ++c) { s.a[c] = 0.f; s.b[c] = 0.f; }
    }
}

__device__ __forceinline__ float wsum3(float m, float c, float p) {
    return fmaf(W_E, m + p, W_C * c);       // W_E*(m+p) + W_C*c
}

// One output row: vertical 3-tap of {a,b,a2,b2,ab} from 3 window rows,
// horizontal 3-tap via intra-wave shuffle halo, SSIM formula, partial sum.
__device__ __forceinline__ float ssim_out_row(const RowRegs& r0, const RowRegs& r1,
                                              const RowRegs& r2,
                                              bool lane0, bool lane63) {
    float v1[8], v2[8], q11[8], q22[8], q12[8];
#pragma unroll
    for (int c = 0; c < 8; ++c) {
        const float a0 = r0.a[c], a1 = r1.a[c], a2 = r2.a[c];
        const float b0 = r0.b[c], b1 = r1.b[c], b2 = r2.b[c];
        v1[c]  = wsum3(a0, a1, a2);
        v2[c]  = wsum3(b0, b1, b2);
        q11[c] = fmaf(W_E, fmaf(a0, a0, a2 * a2), W_C * (a1 * a1));
        q22[c] = fmaf(W_E, fmaf(b0, b0, b2 * b2), W_C * (b1 * b1));
        q12[c] = fmaf(W_E, fmaf(a0, b0, a2 * b2), W_C * (a1 * b1));
    }
    // halo: my col -1 = left lane's col 7; my col 8 = right lane's col 0
    float L1  = __shfl_up(v1[7], 1);    if (lane0)  L1  = 0.f;
    float L2  = __shfl_up(v2[7], 1);    if (lane0)  L2  = 0.f;
    float L11 = __shfl_up(q11[7], 1);   if (lane0)  L11 = 0.f;
    float L22 = __shfl_up(q22[7], 1);   if (lane0)  L22 = 0.f;
    float L12 = __shfl_up(q12[7], 1);   if (lane0)  L12 = 0.f;
    float R1  = __shfl_down(v1[0], 1);  if (lane63) R1  = 0.f;
    float R2  = __shfl_down(v2[0], 1);  if (lane63) R2  = 0.f;
    float R11 = __shfl_down(q11[0], 1); if (lane63) R11 = 0.f;
    float R22 = __shfl_down(q22[0], 1); if (lane63) R22 = 0.f;
    float R12 = __shfl_down(q12[0], 1); if (lane63) R12 = 0.f;

    float sum = 0.f;
#pragma unroll
    for (int c = 0; c < 8; ++c) {
        const float m1  = wsum3(c ? v1[c-1]  : L1,  v1[c],  c < 7 ? v1[c+1]  : R1);
        const float m2  = wsum3(c ? v2[c-1]  : L2,  v2[c],  c < 7 ? v2[c+1]  : R2);
        const float e11 = wsum3(c ? q11[c-1] : L11, q11[c], c < 7 ? q11[c+1] : R11);
        const float e22 = wsum3(c ? q22[c-1] : L22, q22[c], c < 7 ? q22[c+1] : R22);
        const float e12 = wsum3(c ? q12[c-1] : L12, q12[c], c < 7 ? q12[c+1] : R12);
        const float mu1s = m1 * m1, mu2s = m2 * m2, m12 = m1 * m2;
        const float s11 = e11 - mu1s, s22 = e22 - mu2s, s12 = e12 - m12;
        const float num = fmaf(2.f, m12, C1v) * fmaf(2.f, s12, C2v);
        const float den = (mu1s + mu2s + C1v) * (s11 + s22 + C2v);
        // v_rcp_f32: ~1e-7 rel error per term vs 2% abs threshold — negligible
        sum = fmaf(num, __builtin_amdgcn_rcpf(den), sum);
    }
    return sum;
}

__global__ void ssim_init_kernel(double* __restrict__ accum) {
    const int i = blockIdx.x * blockDim.x + threadIdx.x;
    if (i < NSLOT * SLOT_STRIDE) accum[i] = 0.0;
}

// 4 independent waves per block, no LDS, no __syncthreads.
// Wave-task = (plane, 16-row strip); wave spans full 512-px width.
__global__ __launch_bounds__(256, 3) void ssim_main_kernel(
    const float* __restrict__ img1, const float* __restrict__ img2,
    double* __restrict__ accum)
{
    const int t = threadIdx.x;
    const int lane = t & 63;
    const int task = blockIdx.x * 4 + (t >> 6);
    const int plane = task >> 5;            // STRIPS = 32
    const int y0 = (task & 31) * RH;
    const int col0 = lane << 3;
    const bool lane0 = (lane == 0), lane63 = (lane == 63);
    const float* __restrict__ A = img1 + (size_t)plane * PLANE_N;
    const float* __restrict__ B = img2 + (size_t)plane * PLANE_N;

    // 4-slot rolling window (rows yo-1, yo, yo+1, yo+2); unroll-4 => static names
    RowRegs s0, s1, s2, s3;
    load_row(A, B, y0 - 1, col0, s0);
    load_row(A, B, y0,     col0, s1);
    load_row(A, B, y0 + 1, col0, s2);
    load_row(A, B, y0 + 2, col0, s3);

    float tsum = 0.f;
#pragma unroll 1
    for (int m = 0; m < RH; m += 4) {
        const int yo = y0 + m;
        tsum += ssim_out_row(s0, s1, s2, lane0, lane63);
        load_row(A, B, yo + 3, col0, s0);   // consumed 2 compute-rows later
        tsum += ssim_out_row(s1, s2, s3, lane0, lane63);
        load_row(A, B, yo + 4, col0, s1);
        tsum += ssim_out_row(s2, s3, s0, lane0, lane63);
        load_row(A, B, yo + 5, col0, s2);
        tsum += ssim_out_row(s3, s0, s1, lane0, lane63);
        load_row(A, B, yo + 6, col0, s3);
    }

#pragma unroll
    for (int off = 32; off; off >>= 1) tsum += __shfl_xor(tsum, off, 64);
    if (lane == 0)
        atomicAdd(&accum[(task & (NSLOT - 1)) * SLOT_STRIDE], (double)tsum);
}

__global__ void ssim_fin_kernel(const double* __restrict__ accum,
                                float* __restrict__ out) {
    const int lane = threadIdx.x;           // 64 threads
    double v = accum[lane * SLOT_STRIDE];
#pragma unroll
    for (int off = 32; off; off >>= 1) v += __shfl_xor(v, off, 64);
    if (lane == 0) out[0] = 1.0f - (float)v;
}

extern "C" void kernel_launch(void* const* d_in, const int* in_sizes, int n_in,
                              void* d_out, int out_size, void* d_ws, size_t ws_size,
                              hipStream_t stream) {
    const float* img1 = (const float*)d_in[0];
    const float* img2 = (const float*)d_in[1];
    float* out = (float*)d_out;
    double* accum = (double*)d_ws;

    const int planes = in_sizes[0] / PLANE_N;      // 32*3 = 96
    const int tasks = planes * STRIPS;             // 3072
    const int blocks = tasks / 4;                  // 768

    ssim_init_kernel<<<2, 256, 0, stream>>>(accum);
    ssim_main_kernel<<<blocks, 256, 0, stream>>>(img1, img2, accum);
    ssim_fin_kernel<<<1, 64, 0, stream>>>(accum, out);
}

// Round 3
// 261.582 us; speedup vs baseline: 1.2129x; 1.2129x over previous
//
#include <hip/hip_runtime.h>

#define IMG_H 512
#define IMG_W 512
#define RH 16                        // output rows per wave-task
#define STRIPS (IMG_H / RH)          // 32
#define PLANE_N (IMG_H * IMG_W)
#define NSLOT 64
#define SLOT_STRIDE 8                // doubles, 64 B apart: spread atomic traffic

// f32-rounded Gaussian(sigma=1.5, k=3) weights, matching JAX's f32 computation
constexpr float W_E = 0.30780133f;
constexpr float W_C = 0.38439734f;
constexpr float C1v = 1e-4f;
constexpr float C2v = 9e-4f;

// One input row's horizontal 3-tap conv sums for this lane's 4 columns.
struct HRow { float h1[4], h2[4], h11[4], h22[4], h12[4]; };   // 20 VGPRs
// Raw pixel row: 4 cols of each image + the (lane0/lane63 only) edge pixel.
struct Raw { float4 a, b; float aE, bE; };                     // 10 VGPRs

__device__ __forceinline__ void load_row(const float* __restrict__ A,
                                         const float* __restrict__ B,
                                         int row, int col0, int ecol, Raw& r) {
    if ((unsigned)row < (unsigned)IMG_H) {          // wave-uniform
        const size_t off = (size_t)row * IMG_W;
        r.a = *(const float4*)(A + off + col0);
        r.b = *(const float4*)(B + off + col0);
        float ae = 0.f, be = 0.f;
        if (ecol >= 0) {                            // ≤2 active lanes
            ae = A[off + ecol];
            be = B[off + ecol];
        }
        r.aE = ae; r.bE = be;
    } else {                                        // rows -1 / 512 are zero pad
        r.a = make_float4(0.f, 0.f, 0.f, 0.f);
        r.b = make_float4(0.f, 0.f, 0.f, 0.f);
        r.aE = 0.f; r.bE = 0.f;
    }
}

// Horizontal 3-tap of {a, b, a2, b2, ab} for 4 cols; halo via intra-wave
// shuffle, with the wave-edge columns patched from the edge load.
__device__ __forceinline__ void compute_h(const Raw& r, int lane, HRow& H) {
    float aL = __shfl_up(r.a.w, 1);
    float bL = __shfl_up(r.b.w, 1);
    float aR = __shfl_down(r.a.x, 1);
    float bR = __shfl_down(r.b.x, 1);
    if (lane == 0)  { aL = r.aE; bL = r.bE; }
    if (lane == 63) { aR = r.aE; bR = r.bE; }
    const float av[6] = {aL, r.a.x, r.a.y, r.a.z, r.a.w, aR};
    const float bv[6] = {bL, r.b.x, r.b.y, r.b.z, r.b.w, bR};
#pragma unroll
    for (int c = 0; c < 4; ++c) {
        const float am = av[c], a0 = av[c + 1], ap = av[c + 2];
        const float bm = bv[c], b0 = bv[c + 1], bp = bv[c + 2];
        H.h1[c]  = fmaf(W_E, am + ap, W_C * a0);
        H.h2[c]  = fmaf(W_E, bm + bp, W_C * b0);
        H.h11[c] = fmaf(W_E, fmaf(am, am, ap * ap), W_C * (a0 * a0));
        H.h22[c] = fmaf(W_E, fmaf(bm, bm, bp * bp), W_C * (b0 * b0));
        H.h12[c] = fmaf(W_E, fmaf(am, bm, ap * bp), W_C * (a0 * b0));
    }
}

// Vertical 3-tap over window rows (P, Q, R) + SSIM formula; partial sum.
__device__ __forceinline__ float out_row(const HRow& P, const HRow& Q,
                                         const HRow& R) {
    float s = 0.f;
#pragma unroll
    for (int c = 0; c < 4; ++c) {
        const float m1  = fmaf(W_E, P.h1[c]  + R.h1[c],  W_C * Q.h1[c]);
        const float m2  = fmaf(W_E, P.h2[c]  + R.h2[c],  W_C * Q.h2[c]);
        const float e11 = fmaf(W_E, P.h11[c] + R.h11[c], W_C * Q.h11[c]);
        const float e22 = fmaf(W_E, P.h22[c] + R.h22[c], W_C * Q.h22[c]);
        const float e12 = fmaf(W_E, P.h12[c] + R.h12[c], W_C * Q.h12[c]);
        const float mu1s = m1 * m1, mu2s = m2 * m2, m12 = m1 * m2;
        const float s11 = e11 - mu1s, s22 = e22 - mu2s, s12 = e12 - m12;
        const float num = fmaf(2.f, m12, C1v) * fmaf(2.f, s12, C2v);
        const float den = (mu1s + mu2s + C1v) * (s11 + s22 + C2v);
        s = fmaf(num, __builtin_amdgcn_rcpf(den), s);   // ~1e-7 rel vs 2% thr
    }
    return s;
}

__global__ void ssim_init_kernel(double* __restrict__ accum) {
    const int i = blockIdx.x * blockDim.x + threadIdx.x;
    if (i < NSLOT * SLOT_STRIDE) accum[i] = 0.0;
}

// Wave-task = (plane, 16-row strip, 256-col half). 4 independent waves/block,
// no LDS, no barriers. Statically-named slot rotation (3 H-slots x 2 raw
// slots, period 6) => zero register moves, nothing dynamically indexed.
__global__ __launch_bounds__(256, 4) void ssim_main_kernel(
    const float* __restrict__ img1, const float* __restrict__ img2,
    double* __restrict__ accum)
{
    const int t = threadIdx.x;
    const int lane = t & 63;
    const int task = blockIdx.x * 4 + (t >> 6);     // 0..6143
    const int half  = task & 1;
    const int strip = (task >> 1) & (STRIPS - 1);
    const int plane = task >> 6;                    // 96 planes
    const int y0 = strip * RH;
    const int col0 = half * 256 + (lane << 2);
    const float* __restrict__ A = img1 + (size_t)plane * PLANE_N;
    const float* __restrict__ B = img2 + (size_t)plane * PLANE_N;

    // edge column: lane0 needs col0-1, lane63 needs col0+4; -1 = none/border
    int ecol = -1;
    if (lane == 0 && col0 > 0) ecol = col0 - 1;
    if (lane == 63 && col0 + 4 < IMG_W) ecol = col0 + 4;

    HRow HA, HB, HC;
    Raw R0, R1;
    float tsum = 0.f;

    // STANZA k: prefetch next raw row into RL, build Hnew from RU,
    // then (if the window is primed) emit one output row.
#define STANZA(Hm2, Hm1, Hnew, RU, RL, yload, doout)        \
    do {                                                    \
        load_row(A, B, (yload), col0, ecol, (RL));          \
        compute_h((RU), lane, (Hnew));                      \
        if (doout) tsum += out_row((Hm2), (Hm1), (Hnew));   \
    } while (0)

    load_row(A, B, y0 - 1, col0, ecol, R0);
    STANZA(HA, HA, HA, R0, R1, y0,     false);      // k=0: row y0-1 -> HA
    STANZA(HA, HA, HB, R1, R0, y0 + 1, false);      // k=1: row y0   -> HB

#pragma unroll 1
    for (int g = 0; g < 2; ++g) {                   // k = 2..13
        const int yb = y0 + 2 + 6 * g;
        STANZA(HA, HB, HC, R0, R1, yb,     true);
        STANZA(HB, HC, HA, R1, R0, yb + 1, true);
        STANZA(HC, HA, HB, R0, R1, yb + 2, true);
        STANZA(HA, HB, HC, R1, R0, yb + 3, true);
        STANZA(HB, HC, HA, R0, R1, yb + 4, true);
        STANZA(HC, HA, HB, R1, R0, yb + 5, true);
    }
    STANZA(HA, HB, HC, R0, R1, y0 + 14, true);      // k=14
    STANZA(HB, HC, HA, R1, R0, y0 + 15, true);      // k=15
    STANZA(HC, HA, HB, R0, R1, y0 + 16, true);      // k=16
    STANZA(HA, HB, HC, R1, R0, -1,      true);      // k=17 (no next row)
#undef STANZA

#pragma unroll
    for (int off = 32; off; off >>= 1) tsum += __shfl_xor(tsum, off, 64);
    if (lane == 0)
        atomicAdd(&accum[(task & (NSLOT - 1)) * SLOT_STRIDE], (double)tsum);
}

__global__ void ssim_fin_kernel(const double* __restrict__ accum,
                                float* __restrict__ out) {
    const int lane = threadIdx.x;                   // 64 threads
    double v = accum[lane * SLOT_STRIDE];
#pragma unroll
    for (int off = 32; off; off >>= 1) v += __shfl_xor(v, off, 64);
    if (lane == 0) out[0] = 1.0f - (float)v;
}

extern "C" void kernel_launch(void* const* d_in, const int* in_sizes, int n_in,
                              void* d_out, int out_size, void* d_ws, size_t ws_size,
                              hipStream_t stream) {
    const float* img1 = (const float*)d_in[0];
    const float* img2 = (const float*)d_in[1];
    float* out = (float*)d_out;
    double* accum = (double*)d_ws;

    const int planes = in_sizes[0] / PLANE_N;       // 32*3 = 96
    const int tasks = planes * STRIPS * 2;          // 6144 waves
    const int blocks = tasks / 4;                   // 1536

    ssim_init_kernel<<<2, 256, 0, stream>>>(accum);
    ssim_main_kernel<<<blocks, 256, 0, stream>>>(img1, img2, accum);
    ssim_fin_kernel<<<1, 64, 0, stream>>>(accum, out);
}